// Round 1
// 479.373 us; speedup vs baseline: 1.0290x; 1.0290x over previous
//
#include <hip/hip_runtime.h>

// Problem constants: B=2, S=2048, E=1024, H=16, DH=64. All fp32 in/out.
// Pipeline:
//   1) convert q,k,v,Wq,Wk,Wv,Wo fp32->bf16              (1 launch)
//   2) Q = q @ Wq^T + bq  (bf16 NT-GEMM, 128x128 tile)   (3 launches)
//   3) V^T reshape [b][h][d][s] for PV B-fragments       (1 launch)
//   4) fused attention with cross-head logit mixing      (1 launch)
//      S'_g = sum_h M~[g,h] * (Q_h K_h^T), M~ = (I+Wc)/8; bc dropped
//      (constant along k => softmax-invariant). Online softmax, PV accum.
//      v2: register softmax (wave g owns q-row g across all heads),
//      conflict-free LDS (36/580-short strides + XOR slot swizzle),
//      software-pipelined loop (QK(t+1) after PV(t)), global prefetch,
//      XCD-aware block decode (one batch per XCD half).
//   5) out = O @ Wo^T + bo, fp32 to d_out                (1 launch)
// Workspace layout (56 MB total, reuse: O overlays q_bf, VT overlays k_bf).

typedef __attribute__((ext_vector_type(8))) short bf16x8_t;   // 8 bf16 (4 VGPRs)
typedef __attribute__((ext_vector_type(4))) short bf16x4_t;   // 4 bf16 (2 VGPRs)
typedef __attribute__((ext_vector_type(4))) float f32x4_t;    // MFMA accumulator

__device__ inline unsigned short f2bf(float f) {
  unsigned u = __builtin_bit_cast(unsigned, f);
  u += 0x7fffu + ((u >> 16) & 1u);          // round-to-nearest-even
  return (unsigned short)(u >> 16);
}

struct ConvArgs {
  const float* src[7];
  unsigned short* dst[7];
  int n[7];
};

__global__ __launch_bounds__(256) void convert_f32_bf16(ConvArgs a) {
  const int which = blockIdx.y;
  const int i = (blockIdx.x * 256 + threadIdx.x) * 8;
  if (i >= a.n[which]) return;
  const float* s = a.src[which] + i;
  f32x4_t x0 = *(const f32x4_t*)(s);
  f32x4_t x1 = *(const f32x4_t*)(s + 4);
  bf16x8_t o;
#pragma unroll
  for (int j = 0; j < 4; j++) o[j] = (short)f2bf(x0[j]);
#pragma unroll
  for (int j = 0; j < 4; j++) o[4 + j] = (short)f2bf(x1[j]);
  *(bf16x8_t*)(a.dst[which] + i) = o;
}

// C[m][n] = sum_k A[m][k] * Bt[n][k] + bias[n].  M,N,K multiples of 128/128/32.
// 256 threads = 4 waves in 2x2; wave tile 64x64 = 4x4 frags of 16x16; BK=32.
__global__ __launch_bounds__(256) void gemm_bt(
    const unsigned short* __restrict__ A, const unsigned short* __restrict__ Bt,
    const float* __restrict__ bias, void* __restrict__ C,
    int M, int N, int K, int c_is_f32)
{
  __shared__ unsigned short As[128 * 32];
  __shared__ unsigned short Bs[128 * 32];
  const int t = threadIdx.x;
  const int l = t & 63;
  const int w = t >> 6;
  const int quad = l >> 4, n16 = l & 15;
  const int wm = (w & 1) * 64, wn = (w >> 1) * 64;
  const long m0 = (long)blockIdx.x * 128, n0 = (long)blockIdx.y * 128;

  f32x4_t acc[4][4] = {};

  // staging: thread t covers tile row t/4 (+64 on round 1), cols (t%4)*8..+7
  const unsigned short* gA = A + (m0 + (t >> 2)) * (long)K + (t & 3) * 8;
  const unsigned short* gB = Bt + (n0 + (t >> 2)) * (long)K + (t & 3) * 8;
  const long rowskip = 64l * K;

  for (int kt = 0; kt < K; kt += 32) {
    bf16x8_t ra0 = *(const bf16x8_t*)(gA + kt);
    bf16x8_t ra1 = *(const bf16x8_t*)(gA + kt + rowskip);
    bf16x8_t rb0 = *(const bf16x8_t*)(gB + kt);
    bf16x8_t rb1 = *(const bf16x8_t*)(gB + kt + rowskip);
    __syncthreads();                       // protect LDS from prior iter reads
    *(bf16x8_t*)&As[t * 8] = ra0;          // elem (t>>2)*32 + (t&3)*8 == t*8
    *(bf16x8_t*)&As[2048 + t * 8] = ra1;
    *(bf16x8_t*)&Bs[t * 8] = rb0;
    *(bf16x8_t*)&Bs[2048 + t * 8] = rb1;
    __syncthreads();                       // staging visible
    bf16x8_t af[4], bfr[4];
#pragma unroll
    for (int i = 0; i < 4; i++) {
      af[i]  = *(const bf16x8_t*)&As[(wm + i * 16 + n16) * 32 + quad * 8];
      bfr[i] = *(const bf16x8_t*)&Bs[(wn + i * 16 + n16) * 32 + quad * 8];
    }
#pragma unroll
    for (int mi = 0; mi < 4; mi++)
#pragma unroll
      for (int ni = 0; ni < 4; ni++)
        acc[mi][ni] = __builtin_amdgcn_mfma_f32_16x16x32_bf16(af[mi], bfr[ni], acc[mi][ni], 0, 0, 0);
  }

#pragma unroll
  for (int ni = 0; ni < 4; ni++) {
    const long n = n0 + wn + ni * 16 + n16;
    const float bv = bias[n];
#pragma unroll
    for (int mi = 0; mi < 4; mi++) {
#pragma unroll
      for (int r = 0; r < 4; r++) {
        const long m = m0 + wm + mi * 16 + quad * 4 + r;  // D: row=(l>>4)*4+reg, col=l&15
        const float v = acc[mi][ni][r] + bv;
        if (c_is_f32) ((float*)C)[m * N + n] = v;
        else ((unsigned short*)C)[m * N + n] = f2bf(v);
      }
    }
  }
}

// V [b][s][h*64+d] -> VT [b][h][d][s]
__global__ __launch_bounds__(256) void transpose_v(
    const unsigned short* __restrict__ V, unsigned short* __restrict__ VT)
{
  __shared__ unsigned short tile[64][72];   // +8 pad
  const int t = threadIdx.x;
  const int s0 = blockIdx.x * 64, h = blockIdx.y, b = blockIdx.z;
#pragma unroll
  for (int r = 0; r < 2; r++) {
    const int elem = r * 2048 + t * 8;
    const int s = elem >> 6, d = elem & 63;
    *(bf16x8_t*)&tile[s][d] =
        *(const bf16x8_t*)&V[(size_t)(b * 2048 + s0 + s) * 1024 + h * 64 + d];
  }
  __syncthreads();
#pragma unroll
  for (int r = 0; r < 2; r++) {
    const int elem = r * 2048 + t * 8;
    const int d = elem >> 6, sl = elem & 63;
    bf16x8_t o;
#pragma unroll
    for (int j = 0; j < 8; j++) o[j] = (short)tile[sl + j][d];
    *(bf16x8_t*)&VT[((size_t)(b * 16 + h) * 64 + d) * 2048 + s0 + sl] = o;
  }
}

// Fused attention v2. Grid 256 (1-D, XCD-decoded). 1024 threads = 16 waves,
// wave g: QK^T + PV for head g; register online-softmax for q-row g (all heads).
// Per iter (Tk=32): [issue kf(t+1)/vf(t) global loads] -> mix MFMA from sraw
//   -> register softmax -> pack P (cvt_pk) -> pbuf2 + alphabuf -> B2
//   -> O-rescale + PV(t) -> QK(t+1) -> sraw -> B1.
// LDS strides chosen so every hot access is <=2-way (free) on 32 banks:
//   sraw: 36 shorts/col (18 dw, odd*2 -> n16 spans 16 banks), slot = h ^ ((col>>7)<<3)
//   pbuf2: h-stride 580 (4*290 == 8 mod 32 -> 4 quad phases), q-stride 36, b64 reads
__global__ __launch_bounds__(1024) void attention_fused(
    const unsigned short* __restrict__ Qb, const unsigned short* __restrict__ Kb,
    const unsigned short* __restrict__ VT, const float* __restrict__ Wc,
    unsigned short* __restrict__ Obuf)
{
  __shared__ unsigned short sraw[512 * 36];   // [col=q*32+k][slot0..31(+4 pad)]  36864 B
  __shared__ unsigned short pbuf2[16 * 580];  // [h]{q*36 + k}                    18560 B
  __shared__ float alphabuf[256];             // [h][q]
  __shared__ float lbuf[256];                 // [h][q]
  __shared__ unsigned short mmat[256];        // M~[g_out][h] row-major

  const int t = threadIdx.x;
  const int g = t >> 6, l = t & 63;
  const int quad = l >> 4, n16 = l & 15;

  // XCD decode: id%8 = XCD (round-robin heuristic); batch b pinned to an XCD half
  const int id = blockIdx.x;
  const int xcd = id & 7;
  const int b = xcd >> 2;
  const int qb = (xcd & 3) * 32 + (id >> 3);
  const int q0 = qb * 16;

  if (t < 256) {
    const float v = ((((t >> 4) == (t & 15)) ? 1.0f : 0.0f) + Wc[t]) * 0.125f;
    mmat[t] = f2bf(v);
  }
  __syncthreads();

  // mix A-frag: A[m=g_out=n16][k=h=quad*8+j]; zero for k>=16 (so B side there is don't-care)
  bf16x8_t mfrag;
  if (quad < 2) mfrag = *(const bf16x8_t*)&mmat[n16 * 16 + quad * 8];
  else { bf16x8_t z = {0, 0, 0, 0, 0, 0, 0, 0}; mfrag = z; }
  const int c7 = g >> 2;                   // (col>>7) for this wave's mix chunks

  // Q A-frags: A[m=q=n16][k=d]
  bf16x8_t qf[2];
#pragma unroll
  for (int dr = 0; dr < 2; dr++)
    qf[dr] = *(const bf16x8_t*)&Qb[(size_t)(b * 2048 + q0 + n16) * 1024 + g * 64 + dr * 32 + quad * 8];

  const int slot = g ^ (quad << 3);        // sraw h-slot (writer quad == col>>7)
  const unsigned short* kptr = Kb + (size_t)(b * 2048 + n16) * 1024 + g * 64 + quad * 8;
  const unsigned short* vptr = VT + ((size_t)(b * 16 + g) * 64 + n16) * 2048 + quad * 8;

  bf16x8_t kf[2][2], vf[4];
  auto load_kf = [&](int kt) {
#pragma unroll
    for (int kc = 0; kc < 2; kc++)
#pragma unroll
      for (int dr = 0; dr < 2; dr++)
        kf[kc][dr] = *(const bf16x8_t*)(kptr + (size_t)(kt + kc * 16) * 1024 + dr * 32);
  };
  auto load_vf = [&](int kt) {
#pragma unroll
    for (int dc = 0; dc < 4; dc++)
      vf[dc] = *(const bf16x8_t*)(vptr + (size_t)dc * 16 * 2048 + kt);
  };
  auto qk_stage = [&]() {
    f32x4_t sf[2] = {};
#pragma unroll
    for (int kc = 0; kc < 2; kc++)
#pragma unroll
      for (int dr = 0; dr < 2; dr++)
        sf[kc] = __builtin_amdgcn_mfma_f32_16x16x32_bf16(qf[dr], kf[kc][dr], sf[kc], 0, 0, 0);
    // D: row=q=quad*4+r, col=key=kc*16+n16 -> sraw[col=q*32+k][slot]
#pragma unroll
    for (int kc = 0; kc < 2; kc++)
#pragma unroll
      for (int r = 0; r < 4; r++)
        sraw[((quad * 4 + r) * 32 + kc * 16 + n16) * 36 + slot] = f2bf(sf[kc][r]);
  };

  load_kf(0);
  qk_stage();
  __syncthreads();                          // B1(0)

  f32x4_t o[4] = {};
  float m_run[4], l_run[4];
#pragma unroll
  for (int r = 0; r < 4; r++) { m_run[r] = -1e30f; l_run[r] = 0.0f; }

  for (int it = 0; it < 64; ++it) {
    const int kt = it * 32;
    load_vf(kt);                            // consumed at PV below (drains at B2)
    if (it < 63) load_kf(kt + 32);          // consumed at QK(t+1) after B2

    // ---- head mix: S'(16 g_out x 32 col)/wave via 16x16x32 MFMA, 2 chunks ----
    f32x4_t mixd[2];
#pragma unroll
    for (int c2 = 0; c2 < 2; c2++) {
      const int c = g * 2 + c2;             // cols [32g,32g+32) -> q=g, k=c2*16+n16
      const unsigned short* sp = &sraw[(c * 16 + n16) * 36 + (((quad & 1) ^ c7) << 3)];
      bf16x4_t lo = *(const bf16x4_t*)sp;   // ds_read_b64 pair (16B-misaligned rows)
      bf16x4_t hi = *(const bf16x4_t*)(sp + 4);
      bf16x8_t bb = {lo[0], lo[1], lo[2], lo[3], hi[0], hi[1], hi[2], hi[3]};
      f32x4_t z = {};
      mixd[c2] = __builtin_amdgcn_mfma_f32_16x16x32_bf16(mfrag, bb, z, 0, 0, 0);
    }
    // lane holds S'[h=quad*4+r][q=g][k=c2*16+n16]

    // ---- register online softmax (rows (h, q=g); 16-lane max reduce per quad) ----
    float p0[4], p1[4], al[4];
#pragma unroll
    for (int r = 0; r < 4; r++) {
      float mx = fmaxf(mixd[0][r], mixd[1][r]);
      mx = fmaxf(mx, __shfl_xor(mx, 1));
      mx = fmaxf(mx, __shfl_xor(mx, 2));
      mx = fmaxf(mx, __shfl_xor(mx, 4));
      mx = fmaxf(mx, __shfl_xor(mx, 8));
      const float mnew = fmaxf(m_run[r], mx);
      al[r] = __expf(m_run[r] - mnew);
      m_run[r] = mnew;
      p0[r] = __expf(mixd[0][r] - mnew);
      p1[r] = __expf(mixd[1][r] - mnew);
      // l-sum: per-lane partial only (alpha is quad-uniform); reduce in epilogue
      l_run[r] = l_run[r] * al[r] + (p0[r] + p1[r]);
    }

    // ---- pack P to bf16 pairs (neighbor-lane pairing), write pbuf2 ----
    const bool evn = (n16 & 1) == 0;
#pragma unroll
    for (int r = 0; r < 4; r++) {
      const float p0n = __shfl_xor(p0[r], 1);
      const float p1n = __shfl_xor(p1[r], 1);
      const float va = evn ? p0[r] : p1n;   // value at key keven
      const float vb = evn ? p0n : p1[r];   // value at keven+1
      unsigned pk;
      asm volatile("v_cvt_pk_bf16_f32 %0, %1, %2" : "=v"(pk) : "v"(va), "v"(vb));
      const int keven = evn ? n16 : (15 + n16);
      *(unsigned*)&pbuf2[(quad * 4 + r) * 580 + g * 36 + keven] = pk;
    }
    if (n16 == 0) {
#pragma unroll
      for (int r = 0; r < 4; r++) alphabuf[(quad * 4 + r) * 16 + g] = al[r];
    }
    __syncthreads();                        // B2: pbuf2/alphabuf ready; sraw reads done

    // ---- O rescale + PV ----
#pragma unroll
    for (int r = 0; r < 4; r++) {
      const float ar = alphabuf[g * 16 + quad * 4 + r];   // broadcast read
#pragma unroll
      for (int dc = 0; dc < 4; dc++) o[dc][r] *= ar;
    }
    const unsigned short* pp = &pbuf2[g * 580 + n16 * 36 + quad * 8];
    bf16x4_t plo = *(const bf16x4_t*)pp;
    bf16x4_t phi = *(const bf16x4_t*)(pp + 4);
    bf16x8_t pf = {plo[0], plo[1], plo[2], plo[3], phi[0], phi[1], phi[2], phi[3]};
#pragma unroll
    for (int dc = 0; dc < 4; dc++)
      o[dc] = __builtin_amdgcn_mfma_f32_16x16x32_bf16(pf, vf[dc], o[dc], 0, 0, 0);

    if (it < 63) {
      qk_stage();                           // QK(t+1) with prefetched kf
      __syncthreads();                      // B1: sraw(t+1) ready; pbuf2 reads done
    }
  }

  // ---- epilogue: reduce deferred l over the 16 lanes, normalize, store ----
#pragma unroll
  for (int r = 0; r < 4; r++) {
    float s = l_run[r];
    s += __shfl_xor(s, 1);
    s += __shfl_xor(s, 2);
    s += __shfl_xor(s, 4);
    s += __shfl_xor(s, 8);
    l_run[r] = s;
  }
  if (n16 == 0) {
#pragma unroll
    for (int r = 0; r < 4; r++) lbuf[(quad * 4 + r) * 16 + g] = l_run[r];
  }
  __syncthreads();
  float linv[4];
#pragma unroll
  for (int r = 0; r < 4; r++) linv[r] = 1.0f / lbuf[g * 16 + quad * 4 + r];
#pragma unroll
  for (int dc = 0; dc < 4; dc++)
#pragma unroll
    for (int r = 0; r < 4; r++) {
      const float v = o[dc][r] * linv[r];
      Obuf[(size_t)(b * 2048 + q0 + quad * 4 + r) * 1024 + g * 64 + dc * 16 + n16] = f2bf(v);
    }
}

extern "C" void kernel_launch(void* const* d_in, const int* in_sizes, int n_in,
                              void* d_out, int out_size, void* d_ws, size_t ws_size,
                              hipStream_t stream) {
  const float* query = (const float*)d_in[0];
  const float* key   = (const float*)d_in[1];
  const float* value = (const float*)d_in[2];
  const float* Wq = (const float*)d_in[3];
  const float* bq = (const float*)d_in[4];
  const float* Wk = (const float*)d_in[5];
  const float* bk = (const float*)d_in[6];
  const float* Wv = (const float*)d_in[7];
  const float* bv = (const float*)d_in[8];
  const float* Wc = (const float*)d_in[9];
  // d_in[10] = bc: constant along softmax axis -> provably no effect on output
  const float* Wo = (const float*)d_in[11];
  const float* bo = (const float*)d_in[12];

  char* ws = (char*)d_ws;
  const size_t MB = 1024 * 1024;
  unsigned short* q_bf  = (unsigned short*)(ws);            // 8MB; later reused as Obuf
  unsigned short* k_bf  = (unsigned short*)(ws + 8 * MB);   // 8MB; later reused as VT
  unsigned short* v_bf  = (unsigned short*)(ws + 16 * MB);  // 8MB
  unsigned short* wq_bf = (unsigned short*)(ws + 24 * MB);  // 2MB
  unsigned short* wk_bf = (unsigned short*)(ws + 26 * MB);  // 2MB
  unsigned short* wv_bf = (unsigned short*)(ws + 28 * MB);  // 2MB
  unsigned short* wo_bf = (unsigned short*)(ws + 30 * MB);  // 2MB
  unsigned short* Qb    = (unsigned short*)(ws + 32 * MB);  // 8MB
  unsigned short* Kb    = (unsigned short*)(ws + 40 * MB);  // 8MB
  unsigned short* Vb    = (unsigned short*)(ws + 48 * MB);  // 8MB  (total 56MB)
  unsigned short* VT   = k_bf;   // k_bf dead after K-projection
  unsigned short* Obuf = q_bf;   // q_bf dead after Q-projection

  ConvArgs ca;
  ca.src[0] = query; ca.dst[0] = q_bf;  ca.n[0] = 2 * 2048 * 1024;
  ca.src[1] = key;   ca.dst[1] = k_bf;  ca.n[1] = 2 * 2048 * 1024;
  ca.src[2] = value; ca.dst[2] = v_bf;  ca.n[2] = 2 * 2048 * 1024;
  ca.src[3] = Wq;    ca.dst[3] = wq_bf; ca.n[3] = 1024 * 1024;
  ca.src[4] = Wk;    ca.dst[4] = wk_bf; ca.n[4] = 1024 * 1024;
  ca.src[5] = Wv;    ca.dst[5] = wv_bf; ca.n[5] = 1024 * 1024;
  ca.src[6] = Wo;    ca.dst[6] = wo_bf; ca.n[6] = 1024 * 1024;
  convert_f32_bf16<<<dim3(2048, 7), 256, 0, stream>>>(ca);

  gemm_bt<<<dim3(32, 8), 256, 0, stream>>>(q_bf, wq_bf, bq, Qb, 4096, 1024, 1024, 0);
  gemm_bt<<<dim3(32, 8), 256, 0, stream>>>(k_bf, wk_bf, bk, Kb, 4096, 1024, 1024, 0);
  gemm_bt<<<dim3(32, 8), 256, 0, stream>>>(v_bf, wv_bf, bv, Vb, 4096, 1024, 1024, 0);

  transpose_v<<<dim3(32, 16, 2), 256, 0, stream>>>(Vb, VT);

  attention_fused<<<dim3(256), 1024, 0, stream>>>(Qb, Kb, VT, Wc, Obuf);

  gemm_bt<<<dim3(32, 8), 256, 0, stream>>>(Obuf, wo_bf, bo, d_out, 4096, 1024, 1024, 1);
}